// Round 6
// baseline (1876.916 us; speedup 1.0000x reference)
//
#include <hip/hip_runtime.h>
#include <stdint.h>

#define NIMG 8
#define NCLS 80
#define HF 100
#define WF 152
#define NPTS (HF*WF)          // 15200
#define NPC (NPTS*NCLS)       // 1216000
#define SCAN_BLOCKS 297       // ceil(NPC/4096), R1's proven sweep shape
#define TOPK 1000
#define CAP 2048
#define POSTK 100
#define FLOORBIN 1000u        // (0x3E800000>>20): score >= 0.25f
#define PCAP 98304            // per-image pre-candidate cap (96k)
#define FASTB 12              // blocks per image for fast collect

// ---- workspace layout (bytes) ----
static constexpr size_t B_H1    = 0;                           // u32 [8][4096]
static constexpr size_t B_CNT   = B_H1 + (size_t)8*4096*4;     // u32 [8]
static constexpr size_t B_DONE  = B_CNT + 8*4;                 // u32 [8]
static constexpr size_t B_PCNT  = B_DONE + 8*4;                // u32 [8]
static constexpr size_t B_META  = B_PCNT + 8*4;                // u32 [8][4] {c_above,B,fast,-}
static constexpr size_t B_ZEND  = B_META + 8*4*4;              // memset 0 through here
static constexpr size_t B_CAND  = (B_ZEND + 7) & ~(size_t)7;   // u64 [8][CAP]
static constexpr size_t B_BOX   = B_CAND + (size_t)8*CAP*8;    // f32 [8][TOPK][4]
static constexpr size_t B_OBOX  = B_BOX + (size_t)8*TOPK*16;   // f32 [8][TOPK][4]
static constexpr size_t B_SC    = B_OBOX + (size_t)8*TOPK*16;  // f32 [8][TOPK]
static constexpr size_t B_VAL   = B_SC + (size_t)8*TOPK*4;     // u32 [8][TOPK]
static constexpr size_t B_LAB   = B_VAL + (size_t)8*TOPK*4;    // u32 [8][TOPK]
static constexpr size_t B_KEEP  = B_LAB + (size_t)8*TOPK*4;    // u32 [8][TOPK]
static constexpr size_t B_PCAND = (B_KEEP + (size_t)8*TOPK*4 + 7) & ~(size_t)7; // u64 [8][PCAP]
static constexpr size_t B_NEED  = B_PCAND + (size_t)8*PCAP*8;  // ~6.7 MB total

__device__ __forceinline__ float sigm(float x){ return 1.0f / (1.0f + expf(-x)); }

// score for input-layout element e = c*NPTS + p; f = reference flat index p*NCLS + c
// (bit-identical to the passing R1/R2/R3 kernels)
__device__ __forceinline__ float score_at(const float* __restrict__ cls,
                                          const float* __restrict__ ctr,
                                          int e, uint32_t& f){
  int c = e / NPTS;
  int p = e - c * NPTS;
  f = (uint32_t)(p * NCLS + c);
  float s = sigm(cls[e]);
  if (!(s > 0.05f)) return 0.0f;          // cand = cls > PRE_NMS_THRESH
  return s * sigm(ctr[p]);                // cls * centerness
}

// THE single full sweep (R1's proven 99-us shape) + pre-candidate push +
// fused last-block boundary-bin scan and fast-path flag.
__global__ void __launch_bounds__(256)
k_hist(const float* __restrict__ box_cls, const float* __restrict__ ctr,
       uint32_t* __restrict__ h1, uint32_t* __restrict__ done,
       uint32_t* __restrict__ pcnt, uint64_t* __restrict__ pcand,
       uint32_t* __restrict__ meta, int use_pcand){
  __shared__ uint32_t h[4096];
  for (int i = threadIdx.x; i < 4096; i += 256) h[i] = 0;
  __syncthreads();
  const int n = blockIdx.y;
  const int tid = threadIdx.x;
  const float* cls = box_cls + (size_t)n * NPC;
  const float* ct  = ctr + (size_t)n * NPTS;
  uint64_t* pc = pcand + (size_t)n * PCAP;
  const int base = blockIdx.x * 4096;
  for (int k = 0; k < 16; ++k){
    int e = base + k * 256 + tid;
    if (e < NPC){
      uint32_t f; float s = score_at(cls, ct, e, f);
      if (s > 0.0f){
        uint32_t bits = __float_as_uint(s);
        atomicAdd(&h[bits >> 20], 1u);
        if (use_pcand && (bits >> 20) >= FLOORBIN){
          uint32_t pos = atomicAdd(&pcnt[n], 1u);
          if (pos < PCAP)
            pc[pos] = ((uint64_t)bits << 32) | (uint64_t)(0xFFFFFFFFu - f);
        }
      }
    }
  }
  __syncthreads();
  uint32_t* g1 = h1 + (size_t)n * 4096;
  for (int i = tid; i < 4096; i += 256){
    uint32_t v = h[i];
    if (v) atomicAdd(&g1[i], v);
  }
  // ---- fused boundary-bin scan: last finishing block of this image ----
  __threadfence();
  __shared__ uint32_t last;
  if (tid == 0){
    uint32_t prev = __hip_atomic_fetch_add(&done[n], 1u, __ATOMIC_ACQ_REL,
                                           __HIP_MEMORY_SCOPE_AGENT);
    last = (prev == (uint32_t)(SCAN_BLOCKS - 1)) ? 1u : 0u;
  }
  __syncthreads();
  if (!last) return;
  __shared__ uint32_t psum[256];
  __shared__ uint32_t suff[256];
  __shared__ uint32_t sB, sCab;
  uint32_t hv[16];
  uint32_t s = 0;
  #pragma unroll
  for (int i = 0; i < 16; ++i){
    hv[i] = __hip_atomic_load(&g1[tid * 16 + i], __ATOMIC_RELAXED, __HIP_MEMORY_SCOPE_AGENT);
    s += hv[i];
  }
  psum[tid] = s;
  if (tid == 0){ sB = 0u; sCab = 0u; }
  __syncthreads();
  if (tid == 0){
    uint32_t a = 0;
    for (int seg = 255; seg >= 0; --seg){ suff[seg] = a; a += psum[seg]; }
  }
  __syncthreads();
  if (suff[tid] < TOPK && suff[tid] + psum[tid] >= TOPK){
    uint32_t a = suff[tid];
    for (int b = 15; b >= 0; --b){
      uint32_t hb = hv[b];
      if (a + hb >= TOPK){
        sCab = a;
        sB = (uint32_t)(tid * 16 + b);
        break;
      }
      a += hb;
    }
  }
  __syncthreads();
  if (tid == 0){
    uint32_t pcv = __hip_atomic_load(&pcnt[n], __ATOMIC_RELAXED, __HIP_MEMORY_SCOPE_AGENT);
    meta[n * 4 + 0] = sCab;
    meta[n * 4 + 1] = sB;
    meta[n * 4 + 2] = (use_pcand && sB >= FLOORBIN && pcv <= PCAP) ? 1u : 0u;
  }
}

// fast path: scan only the pre-candidates (~45k/image)
__global__ void __launch_bounds__(256)
k_collect_fast(const uint32_t* __restrict__ meta, const uint32_t* __restrict__ pcnt,
               const uint64_t* __restrict__ pcand,
               uint32_t* __restrict__ cnt, uint64_t* __restrict__ cand){
  const int n = blockIdx.y;
  if (meta[n * 4 + 2] == 0u) return;           // full path handles this image
  const uint32_t B = meta[n * 4 + 1];
  uint32_t m = pcnt[n]; if (m > PCAP) m = PCAP;
  const uint64_t* pc = pcand + (size_t)n * PCAP;
  uint64_t* cd = cand + (size_t)n * CAP;
  for (uint32_t i = blockIdx.x * 256 + threadIdx.x; i < m; i += FASTB * 256){
    uint64_t key = pc[i];
    uint32_t bits = (uint32_t)(key >> 32);
    if ((bits >> 20) >= B){
      uint32_t pos = atomicAdd(&cnt[n], 1u);
      if (pos < CAP) cd[pos] = key;
    }
  }
}

// fallback: R1-verbatim full sweep; early-exits per image when fast path taken
__global__ void __launch_bounds__(256)
k_collect_full(const float* __restrict__ box_cls, const float* __restrict__ ctr,
               const uint32_t* __restrict__ meta,
               uint32_t* __restrict__ cnt, uint64_t* __restrict__ cand){
  const int n = blockIdx.y;
  if (meta[n * 4 + 2] != 0u) return;           // fast path already did this image
  const uint32_t B = meta[n * 4 + 1];
  const float* cls = box_cls + (size_t)n * NPC;
  const float* ct  = ctr + (size_t)n * NPTS;
  uint64_t* cd = cand + (size_t)n * CAP;
  const int base = blockIdx.x * 4096;
  for (int k = 0; k < 16; ++k){
    int e = base + k * 256 + threadIdx.x;
    if (e < NPC){
      uint32_t f; float s = score_at(cls, ct, e, f);
      if (s > 0.0f){
        uint32_t bits = __float_as_uint(s);
        if ((bits >> 20) >= B){
          uint32_t pos = atomicAdd(&cnt[n], 1u);
          if (pos < CAP)
            cd[pos] = ((uint64_t)bits << 32) | (uint64_t)(0xFFFFFFFFu - f);
        }
      }
    }
  }
}

// sort candidates (value desc, index asc), take top-1000, decode boxes
__global__ void __launch_bounds__(1024)
k_sort_decode(const uint32_t* __restrict__ cnt, const uint64_t* __restrict__ cand,
              const float* __restrict__ locations, const float* __restrict__ box_reg,
              const float* __restrict__ im_info,
              float* __restrict__ boxw, float* __restrict__ oboxw, float* __restrict__ scw,
              uint32_t* __restrict__ valw, uint32_t* __restrict__ labw){
  __shared__ uint64_t key[2048];
  const int n = blockIdx.x;
  const int t = threadIdx.x;
  int nc = (int)cnt[n]; if (nc > CAP) nc = CAP;
  const uint64_t* cd = cand + (size_t)n * CAP;
  key[t]        = (t < nc) ? cd[t] : 0ull;
  key[t + 1024] = (t + 1024 < nc) ? cd[t + 1024] : 0ull;
  __syncthreads();
  for (int k = 2; k <= 2048; k <<= 1){
    for (int j = k >> 1; j > 0; j >>= 1){
      #pragma unroll
      for (int m = 0; m < 2; ++m){
        int i = t + m * 1024;
        int ixj = i ^ j;
        if (ixj > i){
          uint64_t a = key[i], b = key[ixj];
          bool desc = ((i & k) == 0);
          bool sw = desc ? (a < b) : (a > b);
          if (sw){ key[i] = b; key[ixj] = a; }
        }
      }
      __syncthreads();
    }
  }
  if (t < TOPK){
    uint64_t kk = key[t];
    uint32_t bits = (uint32_t)(kk >> 32);
    uint32_t fi = 0xFFFFFFFFu - (uint32_t)(kk & 0xFFFFFFFFull);
    float v = __uint_as_float(bits);
    int loc = 0, ci = 0;
    if (v > 0.0f){ loc = (int)(fi / NCLS); ci = (int)(fi - (uint32_t)loc * NCLS); }
    float px = locations[2 * loc], py = locations[2 * loc + 1];
    const float* rg = box_reg + (size_t)n * 4 * NPTS;
    float rl = rg[loc], rt = rg[NPTS + loc], rr = rg[2 * NPTS + loc], rb = rg[3 * NPTS + loc];
    float h_im = im_info[n * 2 + 0], w_im = im_info[n * 2 + 1];
    float x1 = fminf(fmaxf(px - rl, 0.0f), w_im - 1.0f);
    float y1 = fminf(fmaxf(py - rt, 0.0f), h_im - 1.0f);
    float x2 = fminf(fmaxf(px + rr, 0.0f), w_im - 1.0f);
    float y2 = fminf(fmaxf(py + rb, 0.0f), h_im - 1.0f);
    bool valid = (v > 0.0f) && (__fsub_rn(x2, x1) >= 0.0f) && (__fsub_rn(y2, y1) >= 0.0f);
    float scv = valid ? v : 0.0f;
    float lab = (float)(ci + 1);
    float off = __fmul_rn(lab, 100000.0f);   // CLASS_OFFSET, mul then add (no fma) like ref
    size_t b4 = ((size_t)n * TOPK + t) * 4;
    boxw[b4 + 0] = x1; boxw[b4 + 1] = y1; boxw[b4 + 2] = x2; boxw[b4 + 3] = y2;
    oboxw[b4 + 0] = __fadd_rn(x1, off); oboxw[b4 + 1] = __fadd_rn(y1, off);
    oboxw[b4 + 2] = __fadd_rn(x2, off); oboxw[b4 + 3] = __fadd_rn(y2, off);
    size_t b1 = (size_t)n * TOPK + t;
    scw[b1] = scv; valw[b1] = valid ? 1u : 0u; labw[b1] = (uint32_t)(ci + 1);
  }
}

// greedy NMS per (image,class); each block gathers its class's indices by ballot
__global__ void __launch_bounds__(64)
k_nms(const uint32_t* __restrict__ labw, const float* __restrict__ oboxw,
      const uint32_t* __restrict__ valw, uint32_t* __restrict__ keepw){
  const int n = blockIdx.y;
  const int c = blockIdx.x;
  const int L = threadIdx.x;
  __shared__ uint16_t list[TOPK];
  const uint32_t* lw = labw + (size_t)n * TOPK;
  uint32_t run = 0;
  #pragma unroll
  for (int j = 0; j < (TOPK + 63) / 64; ++j){
    int idx = j * 64 + L;
    bool m = (idx < TOPK) && (lw[idx] == (uint32_t)(c + 1));
    unsigned long long mask = __ballot(m);
    if (m){
      int pos = (int)run + __popcll(mask & ((1ull << L) - 1ull));
      list[pos] = (uint16_t)idx;
    }
    run += (uint32_t)__popcll(mask);
  }
  __syncthreads();
  const uint32_t kcnt = run;
  if (kcnt == 0) return;
  if (kcnt <= 64){
    int gi = 0, kp = 0;
    float b0 = 0, b1 = 0, b2 = 0, b3 = 0, ar = 0;
    if (L < (int)kcnt){
      gi = (int)list[L];
      size_t a4 = ((size_t)n * TOPK + gi) * 4;
      b0 = oboxw[a4 + 0]; b1 = oboxw[a4 + 1]; b2 = oboxw[a4 + 2]; b3 = oboxw[a4 + 3];
      kp = (valw[n * TOPK + gi] != 0) ? 1 : 0;
      ar = __fmul_rn(fmaxf(__fsub_rn(b2, b0), 0.0f), fmaxf(__fsub_rn(b3, b1), 0.0f));
    }
    for (int i = 0; i + 1 < (int)kcnt; ++i){
      int alive = __shfl(kp, i);
      float xi0 = __shfl(b0, i), xi1 = __shfl(b1, i), xi2 = __shfl(b2, i), xi3 = __shfl(b3, i);
      float ai = __shfl(ar, i);
      if (alive && L > i && kp){
        float ltx = fmaxf(xi0, b0), lty = fmaxf(xi1, b1);
        float rbx = fminf(xi2, b2), rby = fminf(xi3, b3);
        float w = fmaxf(__fsub_rn(rbx, ltx), 0.0f);
        float h = fmaxf(__fsub_rn(rby, lty), 0.0f);
        float inter = __fmul_rn(w, h);
        float den = __fadd_rn(__fsub_rn(__fadd_rn(ai, ar), inter), 1e-9f);
        if (inter / den > 0.6f) kp = 0;
      }
    }
    if (L < (int)kcnt) keepw[n * TOPK + gi] = (uint32_t)kp;
  } else if (L == 0){
    // slow path (kcnt > 64): sequential, correctness-only (statistically never hit)
    for (uint32_t i = 0; i < kcnt; ++i){
      int gi = (int)list[i];
      keepw[n * TOPK + gi] = valw[n * TOPK + gi];
    }
    for (uint32_t i = 0; i < kcnt; ++i){
      int gi = (int)list[i];
      if (!keepw[n * TOPK + gi]) continue;
      size_t a4 = ((size_t)n * TOPK + gi) * 4;
      float x0 = oboxw[a4], x1 = oboxw[a4 + 1], x2 = oboxw[a4 + 2], x3 = oboxw[a4 + 3];
      float ai = __fmul_rn(fmaxf(__fsub_rn(x2, x0), 0.0f), fmaxf(__fsub_rn(x3, x1), 0.0f));
      for (uint32_t j = i + 1; j < kcnt; ++j){
        int gj = (int)list[j];
        if (!keepw[n * TOPK + gj]) continue;
        size_t c4 = ((size_t)n * TOPK + gj) * 4;
        float y0 = oboxw[c4], y1 = oboxw[c4 + 1], y2 = oboxw[c4 + 2], y3 = oboxw[c4 + 3];
        float aj = __fmul_rn(fmaxf(__fsub_rn(y2, y0), 0.0f), fmaxf(__fsub_rn(y3, y1), 0.0f));
        float ltx = fmaxf(x0, y0), lty = fmaxf(x1, y1);
        float rbx = fminf(x2, y2), rby = fminf(x3, y3);
        float w = fmaxf(__fsub_rn(rbx, ltx), 0.0f);
        float h = fmaxf(__fsub_rn(rby, lty), 0.0f);
        float inter = __fmul_rn(w, h);
        float den = __fadd_rn(__fsub_rn(__fadd_rn(ai, aj), inter), 1e-9f);
        if (inter / den > 0.6f) keepw[n * TOPK + gj] = 0;
      }
    }
  }
}

// parallel compaction of kept (score-sorted) entries; first 100 rows, rest zero
__global__ void __launch_bounds__(256)
k_final(const uint32_t* __restrict__ keepw, const float* __restrict__ boxw,
        const uint32_t* __restrict__ labw, const float* __restrict__ scw,
        float* __restrict__ out){
  const int n = blockIdx.x;
  const int t = threadIdx.x;
  __shared__ uint32_t part[256];
  uint32_t f[4]; uint32_t cl = 0;
  const int base = t * 4;
  #pragma unroll
  for (int q = 0; q < 4; ++q){
    int i = base + q;
    f[q] = (i < TOPK) ? keepw[n * TOPK + i] : 0u;
    cl += (f[q] ? 1u : 0u);
  }
  part[t] = cl;
  __syncthreads();
  if (t == 0){
    uint32_t a = 0;
    for (int i = 0; i < 256; ++i){ uint32_t v = part[i]; part[i] = a; a += v; }
  }
  __syncthreads();
  float* outn = out + (size_t)n * POSTK * 6;
  for (int i = t; i < POSTK * 6; i += 256) outn[i] = 0.0f;
  __syncthreads();
  uint32_t off = part[t];
  #pragma unroll
  for (int q = 0; q < 4; ++q){
    int i = base + q;
    if (i < TOPK && f[q]){
      if (off < POSTK){
        float* row = outn + (size_t)off * 6;
        size_t b4 = ((size_t)n * TOPK + i) * 4;
        row[0] = boxw[b4]; row[1] = boxw[b4 + 1]; row[2] = boxw[b4 + 2]; row[3] = boxw[b4 + 3];
        row[4] = (float)labw[n * TOPK + i]; row[5] = scw[n * TOPK + i];
      }
      off++;
    }
  }
}

extern "C" void kernel_launch(void* const* d_in, const int* in_sizes, int n_in,
                              void* d_out, int out_size, void* d_ws, size_t ws_size,
                              hipStream_t stream){
  const float* locations = (const float*)d_in[0];
  const float* box_cls   = (const float*)d_in[1];
  const float* box_reg   = (const float*)d_in[2];
  const float* ctr       = (const float*)d_in[3];
  const float* im_info   = (const float*)d_in[4];
  float* out = (float*)d_out;
  char* ws = (char*)d_ws;
  uint32_t* h1    = (uint32_t*)(ws + B_H1);
  uint32_t* cnt   = (uint32_t*)(ws + B_CNT);
  uint32_t* done  = (uint32_t*)(ws + B_DONE);
  uint32_t* pcnt  = (uint32_t*)(ws + B_PCNT);
  uint32_t* meta  = (uint32_t*)(ws + B_META);
  uint64_t* cand  = (uint64_t*)(ws + B_CAND);
  float*    boxw  = (float*)(ws + B_BOX);
  float*    oboxw = (float*)(ws + B_OBOX);
  float*    scw   = (float*)(ws + B_SC);
  uint32_t* valw  = (uint32_t*)(ws + B_VAL);
  uint32_t* labw  = (uint32_t*)(ws + B_LAB);
  uint32_t* keepw = (uint32_t*)(ws + B_KEEP);
  uint64_t* pcand = (uint64_t*)(ws + B_PCAND);

  // host-side, deterministic: fast path only if the workspace can hold pcand
  const int use_pcand = (ws_size >= B_NEED) ? 1 : 0;

  hipMemsetAsync(d_ws, 0, B_ZEND, stream);
  dim3 scang(SCAN_BLOCKS, NIMG);
  k_hist<<<scang, 256, 0, stream>>>(box_cls, ctr, h1, done, pcnt, pcand, meta, use_pcand);
  k_collect_fast<<<dim3(FASTB, NIMG), 256, 0, stream>>>(meta, pcnt, pcand, cnt, cand);
  k_collect_full<<<scang, 256, 0, stream>>>(box_cls, ctr, meta, cnt, cand);
  k_sort_decode<<<NIMG, 1024, 0, stream>>>(cnt, cand, locations, box_reg, im_info,
                                           boxw, oboxw, scw, valw, labw);
  k_nms<<<dim3(NCLS, NIMG), 64, 0, stream>>>(labw, oboxw, valw, keepw);
  k_final<<<NIMG, 256, 0, stream>>>(keepw, boxw, labw, scw, out);
}